// Round 1
// baseline (628.786 us; speedup 1.0000x reference)
//
#include <hip/hip_runtime.h>
#include <math.h>
#include <stdint.h>

#define B_ 32
#define C_ 32
#define H_ 16
#define V_ 8192
#define HW_ 256
#define NELEM (B_*C_*H_*H_)   // 262144

__device__ __forceinline__ unsigned int fkey(float f) {
    unsigned int u = __float_as_uint(f);
    return (u & 0x80000000u) ? ~u : (u | 0x80000000u);
}

__global__ void __launch_bounds__(256) k_init(
    const float* __restrict__ f, const float* __restrict__ emb,
    float* __restrict__ f_rest, float* __restrict__ f_hat,
    float* __restrict__ e2, float* __restrict__ lossAcc)
{
    int i = blockIdx.x*256 + threadIdx.x;
    if (i < NELEM) { float v = f[i]; f_rest[i] = v; f_hat[i] = 0.f; }
    if (i < V_) {
        const float4* e4 = (const float4*)(emb + (size_t)i*C_);
        float s = 0.f;
        #pragma unroll
        for (int cc = 0; cc < 8; ++cc) {
            float4 ev = e4[cc];
            s += ev.x*ev.x + ev.y*ev.y + ev.z*ev.z + ev.w*ev.w;
        }
        e2[i] = s;
    }
    if (i == 0) lossAcc[0] = 0.f;
}

// area pool f_rest -> z[n][c]; also init best slots
__global__ void __launch_bounds__(256) k_pool(
    const float* __restrict__ f_rest, float* __restrict__ z,
    unsigned long long* __restrict__ best, int pn, int N)
{
    int gid = blockIdx.x*256 + threadIdx.x;
    if (gid >= N*C_) return;
    int c = gid & 31;
    int n = gid >> 5;
    if (c == 0) best[n] = ~0ull;
    int pp = pn*pn;
    int b = n / pp;
    int rem = n - b*pp;
    int p = rem / pn;
    int q = rem - p*pn;
    int hs = (p*H_)/pn,  he = ((p+1)*H_ + pn-1)/pn;
    int ws = (q*H_)/pn,  we = ((q+1)*H_ + pn-1)/pn;
    const float* base = f_rest + ((size_t)(b*C_ + c))*HW_;
    float s = 0.f;
    for (int hh = hs; hh < he; ++hh) {
        #pragma unroll 4
        for (int ww = ws; ww < we; ++ww)
            s += base[hh*H_ + ww];
    }
    float inv = (1.f/(float)(he-hs)) * (1.f/(float)(we-ws));
    z[(size_t)n*C_ + c] = s * inv;
}

// VQ: each lane owns one query row; wave covers a V-chunk; atomicMin-combine
__global__ void __launch_bounds__(256) k_vq(
    const float* __restrict__ z, const float* __restrict__ emb,
    const float* __restrict__ e2, unsigned long long* __restrict__ best,
    int N, int qtiles, int lvs)
{
    int w_in_b = __builtin_amdgcn_readfirstlane((int)(threadIdx.x >> 6));
    int lane = threadIdx.x & 63;
    int wave = blockIdx.x*4 + w_in_b;
    if (wave >= (qtiles << lvs)) return;
    int vs   = 1 << lvs;
    int qt   = wave >> lvs;
    int vc   = wave & (vs-1);
    int vlen = V_ >> lvs;
    int v0   = vc * vlen;
    int n    = qt*64 + lane;
    bool act = (n < N);
    const float4* zp = (const float4*)(z + (size_t)(act ? n : 0)*C_);
    float zr[32];
    #pragma unroll
    for (int cc = 0; cc < 8; ++cc) {
        float4 t = zp[cc];
        zr[cc*4+0]=t.x; zr[cc*4+1]=t.y; zr[cc*4+2]=t.z; zr[cc*4+3]=t.w;
    }
    float z2 = 0.f;
    #pragma unroll
    for (int c = 0; c < 32; ++c) z2 = fmaf(zr[c], zr[c], z2);

    float dmin = __builtin_inff();
    int imin = 0;
    const float4* eb = (const float4*)emb;
    #pragma unroll 2
    for (int v = v0; v < v0 + vlen; ++v) {
        const float4* e4 = eb + (size_t)v*8;
        float a0=0.f, a1=0.f, a2=0.f, a3=0.f;
        #pragma unroll
        for (int cc = 0; cc < 8; ++cc) {
            float4 ev = e4[cc];
            a0 = fmaf(zr[cc*4+0], ev.x, a0);
            a1 = fmaf(zr[cc*4+1], ev.y, a1);
            a2 = fmaf(zr[cc*4+2], ev.z, a2);
            a3 = fmaf(zr[cc*4+3], ev.w, a3);
        }
        float dot = (a0+a1)+(a2+a3);
        float d = (z2 + e2[v]) - 2.f*dot;
        if (d < dmin) { dmin = d; imin = v; }
    }
    if (act) {
        unsigned long long key =
            ((unsigned long long)fkey(dmin) << 32) | (unsigned int)imin;
        atomicMin(best + n, key);
    }
}

__device__ __forceinline__ void cubic_taps(int i, int pn, float* wt, int* col) {
    double src = ((double)i + 0.5) * ((double)pn / 16.0) - 0.5;
    double fl = floor(src);
    const double A = -0.75;
    #pragma unroll
    for (int k = 0; k < 4; ++k) {
        double j = fl - 1.0 + (double)k;
        double d = fabs(src - j);
        double w;
        if (d <= 1.0)      w = ((A+2.0)*d - (A+3.0))*d*d + 1.0;
        else if (d < 2.0)  w = ((A*d - 5.0*A)*d + 8.0*A)*d - 4.0*A;
        else               w = 0.0;
        wt[k] = (float)w;
        int jj = (int)j;
        col[k] = jj < 0 ? 0 : (jj > pn-1 ? pn-1 : jj);
    }
}

// bicubic upsample (emb gather) -> LDS, 3x3 conv + Phi blend,
// f_hat += , f_rest -= , loss partial
__global__ void __launch_bounds__(256) k_upphi(
    const unsigned long long* __restrict__ best,
    const float* __restrict__ emb,
    const float* __restrict__ cw, const float* __restrict__ cb,
    const float* __restrict__ forig,
    float* __restrict__ f_hat, float* __restrict__ f_rest,
    float* __restrict__ lossAcc, int pn)
{
    __shared__ float hup[16][16][33];
    __shared__ float red[4];
    int bi = blockIdx.x >> 3;
    int g  = blockIdx.x & 7;
    int tid = threadIdx.x;
    int h = tid >> 4, w = tid & 15;

    float wh[4]; int th[4];
    float wwt[4]; int tw[4];
    cubic_taps(h, pn, wh, th);
    cubic_taps(w, pn, wwt, tw);

    float acc[32];
    #pragma unroll
    for (int c = 0; c < 32; ++c) acc[c] = 0.f;
    const unsigned long long* bptr = best + bi*pn*pn;
    for (int i = 0; i < 4; ++i) {
        if (wh[i] == 0.f) continue;
        for (int j = 0; j < 4; ++j) {
            float wt = wh[i]*wwt[j];
            if (wt == 0.f) continue;
            unsigned int idx = (unsigned int)(bptr[th[i]*pn + tw[j]] & 0xffffffffull);
            const float4* e4 = (const float4*)(emb + (size_t)idx*C_);
            #pragma unroll
            for (int cc = 0; cc < 8; ++cc) {
                float4 ev = e4[cc];
                acc[cc*4+0] = fmaf(wt, ev.x, acc[cc*4+0]);
                acc[cc*4+1] = fmaf(wt, ev.y, acc[cc*4+1]);
                acc[cc*4+2] = fmaf(wt, ev.z, acc[cc*4+2]);
                acc[cc*4+3] = fmaf(wt, ev.w, acc[cc*4+3]);
            }
        }
    }
    #pragma unroll
    for (int c = 0; c < 32; ++c) hup[h][w][c] = acc[c];
    __syncthreads();

    int co0 = g*4;
    float o4[4];
    #pragma unroll
    for (int k = 0; k < 4; ++k) o4[k] = cb[co0+k];
    for (int ci = 0; ci < 32; ++ci) {
        float hv[9];
        #pragma unroll
        for (int dh = 0; dh < 3; ++dh) {
            int hh = h + dh - 1;
            #pragma unroll
            for (int dw = 0; dw < 3; ++dw) {
                int ww2 = w + dw - 1;
                bool ok = (hh >= 0) & (hh < 16) & (ww2 >= 0) & (ww2 < 16);
                hv[dh*3+dw] = ok ? hup[hh & 15][ww2 & 15][ci] : 0.f;
            }
        }
        #pragma unroll
        for (int k = 0; k < 4; ++k) {
            const float* wr = cw + ((size_t)(co0+k)*C_ + ci)*9;
            float s = 0.f;
            #pragma unroll
            for (int p2 = 0; p2 < 9; ++p2) s = fmaf(hv[p2], wr[p2], s);
            o4[k] += s;
        }
    }

    float sq = 0.f;
    #pragma unroll
    for (int k = 0; k < 4; ++k) {
        float hv0 = hup[h][w][co0+k];
        float outv = 0.5f*hv0 + 0.5f*o4[k];
        size_t off = ((size_t)(bi*C_ + co0 + k))*HW_ + h*16 + w;
        float fh = f_hat[off] + outv;
        f_hat[off] = fh;
        f_rest[off] = f_rest[off] - outv;
        float df = fh - forig[off];
        sq = fmaf(df, df, sq);
    }
    #pragma unroll
    for (int o2 = 32; o2 > 0; o2 >>= 1) sq += __shfl_down(sq, o2, 64);
    if ((tid & 63) == 0) red[tid >> 6] = sq;
    __syncthreads();
    if (tid == 0) atomicAdd(lossAcc, (red[0]+red[1])+(red[2]+red[3]));
}

__global__ void __launch_bounds__(256) k_final(
    const float* __restrict__ f_hat, const float* __restrict__ lossAcc,
    float* __restrict__ out)
{
    int i = blockIdx.x*256 + threadIdx.x;
    if (i < NELEM) out[i] = f_hat[i];
    if (i == 0) out[NELEM] = lossAcc[0] * 1.25f / ((float)NELEM * 10.f);
}

extern "C" void kernel_launch(void* const* d_in, const int* in_sizes, int n_in,
                              void* d_out, int out_size, void* d_ws, size_t ws_size,
                              hipStream_t stream)
{
    const float* f   = (const float*)d_in[0];
    const float* emb = (const float*)d_in[1];
    const float* cw  = (const float*)d_in[2];
    const float* cb  = (const float*)d_in[3];
    float* out = (float*)d_out;
    char* ws = (char*)d_ws;
    unsigned long long* best = (unsigned long long*)ws;       // 8192 * 8 B
    float* f_rest = (float*)(ws + 65536);
    float* f_hat  = f_rest + NELEM;
    float* z      = f_hat + NELEM;
    float* e2     = z + NELEM;
    float* lossAcc = e2 + V_;

    // Replicate PHI_IDX with numpy-linspace double semantics (no FP contraction)
    volatile double a   = 1.0/3.0/4.0;
    volatile double bb  = 1.0 - a;
    volatile double stp = (bb - a) / 3.0;
    double ticks[4];
    for (int i = 0; i < 4; ++i) { volatile double m = (double)i * stp; ticks[i] = m + a; }
    ticks[3] = bb;
    static const int pns[10] = {1,2,3,4,5,6,8,10,13,16};
    int phi_idx[10];
    for (int si = 0; si < 10; ++si) {
        volatile double x = (double)si / 9.0;
        int bi = 0; double bd = fabs(ticks[0] - x);
        for (int k = 1; k < 4; ++k) {
            double d = fabs(ticks[k] - x);
            if (d < bd) { bd = d; bi = k; }
        }
        phi_idx[si] = bi;
    }

    k_init<<<1024, 256, 0, stream>>>(f, emb, f_rest, f_hat, e2, lossAcc);

    static const int lvss[10] = {7,7,7,7,7,7,6,5,4,4};  // V-split log2 per scale
    for (int si = 0; si < 10; ++si) {
        int pn = pns[si];
        int N = B_*pn*pn;
        int pthr = N*C_;
        k_pool<<<(pthr+255)/256, 256, 0, stream>>>(f_rest, z, best, pn, N);
        int qtiles = (N+63)/64;
        int lvs = lvss[si];
        int waves = qtiles << lvs;
        k_vq<<<(waves+3)/4, 256, 0, stream>>>(z, emb, e2, best, N, qtiles, lvs);
        const float* cwp = cw + (size_t)phi_idx[si]*C_*C_*9;
        const float* cbp = cb + (size_t)phi_idx[si]*C_;
        k_upphi<<<B_*8, 256, 0, stream>>>(best, emb, cwp, cbp, f, f_hat, f_rest,
                                          lossAcc, pn);
    }
    k_final<<<1024, 256, 0, stream>>>(f_hat, lossAcc, out);
}

// Round 2
// 610.384 us; speedup vs baseline: 1.0301x; 1.0301x over previous
//
#include <hip/hip_runtime.h>
#include <math.h>
#include <stdint.h>

#define B_ 32
#define C_ 32
#define H_ 16
#define V_ 8192
#define HW_ 256
#define NELEM (B_*C_*H_*H_)   // 262144
#define ESTRIDE 36            // padded emb row: 32 floats + e2 + 3 pad (144 B)

typedef float f32x16 __attribute__((ext_vector_type(16)));

__device__ __forceinline__ unsigned int fkey(float f) {
    unsigned int u = __float_as_uint(f);
    return (u & 0x80000000u) ? ~u : (u | 0x80000000u);
}

// scalar-pipe load of one padded emb row (wave-uniform address)
__device__ __forceinline__ void sload_row(const float* p, f32x16& a, f32x16& b, float& e) {
    asm volatile("s_load_dwordx16 %0, %3, 0x0\n\t"
                 "s_load_dwordx16 %1, %3, 0x40\n\t"
                 "s_load_dword    %2, %3, 0x80"
                 : "=&s"(a), "=&s"(b), "=&s"(e)
                 : "s"(p));
}

__global__ void __launch_bounds__(256) k_init(
    const float* __restrict__ f, const float* __restrict__ emb,
    float* __restrict__ f_rest, float* __restrict__ f_hat,
    float* __restrict__ embp, float* __restrict__ lossAcc)
{
    int i = blockIdx.x*256 + threadIdx.x;
    if (i < NELEM) { float v = f[i]; f_rest[i] = v; f_hat[i] = 0.f; }
    if (i < V_) {
        const float4* e4 = (const float4*)(emb + (size_t)i*C_);
        float4* op = (float4*)(embp + (size_t)i*ESTRIDE);
        float s = 0.f;
        #pragma unroll
        for (int cc = 0; cc < 8; ++cc) {
            float4 ev = e4[cc];
            op[cc] = ev;
            s += ev.x*ev.x + ev.y*ev.y + ev.z*ev.z + ev.w*ev.w;
        }
        embp[(size_t)i*ESTRIDE + 32] = s;
    }
    if (i == 0) lossAcc[0] = 0.f;
}

// area pool f_rest -> z[n][c]; also init best slots
__global__ void __launch_bounds__(256) k_pool(
    const float* __restrict__ f_rest, float* __restrict__ z,
    unsigned long long* __restrict__ best, int pn, int N)
{
    int gid = blockIdx.x*256 + threadIdx.x;
    if (gid >= N*C_) return;
    int c = gid & 31;
    int n = gid >> 5;
    if (c == 0) best[n] = ~0ull;
    int pp = pn*pn;
    int b = n / pp;
    int rem = n - b*pp;
    int p = rem / pn;
    int q = rem - p*pn;
    int hs = (p*H_)/pn,  he = ((p+1)*H_ + pn-1)/pn;
    int ws = (q*H_)/pn,  we = ((q+1)*H_ + pn-1)/pn;
    const float* base = f_rest + ((size_t)(b*C_ + c))*HW_;
    float s = 0.f;
    for (int hh = hs; hh < he; ++hh) {
        #pragma unroll 4
        for (int ww = ws; ww < we; ++ww)
            s += base[hh*H_ + ww];
    }
    float inv = (1.f/(float)(he-hs)) * (1.f/(float)(we-ws));
    z[(size_t)n*C_ + c] = s * inv;
}

// VQ: lane = query; emb rows stream through SGPRs (scalar pipe), ping-pong
#define VSTEP(Ar, Br, Er, VV)                                               \
    {                                                                       \
        float a0=0.f, a1=0.f, a2=0.f, a3=0.f;                               \
        _Pragma("unroll")                                                   \
        for (int cc = 0; cc < 4; ++cc) {                                    \
            a0 = fmaf(zr[4*cc+0], Ar[4*cc+0], a0);                          \
            a1 = fmaf(zr[4*cc+1], Ar[4*cc+1], a1);                          \
            a2 = fmaf(zr[4*cc+2], Ar[4*cc+2], a2);                          \
            a3 = fmaf(zr[4*cc+3], Ar[4*cc+3], a3);                          \
        }                                                                   \
        _Pragma("unroll")                                                   \
        for (int cc = 0; cc < 4; ++cc) {                                    \
            a0 = fmaf(zr[16+4*cc+0], Br[4*cc+0], a0);                       \
            a1 = fmaf(zr[16+4*cc+1], Br[4*cc+1], a1);                       \
            a2 = fmaf(zr[16+4*cc+2], Br[4*cc+2], a2);                       \
            a3 = fmaf(zr[16+4*cc+3], Br[4*cc+3], a3);                       \
        }                                                                   \
        float dot = (a0+a1)+(a2+a3);                                        \
        float d = fmaf(-2.f, dot, Er);                                      \
        if (d < dmin) { dmin = d; imin = (VV); }                            \
    }

__global__ void __launch_bounds__(256) k_vq(
    const float* __restrict__ z, const float* __restrict__ embp,
    unsigned long long* __restrict__ best, int N, int lvs)
{
    __shared__ unsigned long long lb[64];
    int tid  = threadIdx.x;
    int lane = tid & 63;
    int w_in_b = __builtin_amdgcn_readfirstlane(tid >> 6);
    int wave = blockIdx.x*4 + w_in_b;
    int vs   = 1 << lvs;
    int qt   = wave >> lvs;
    int vc   = wave & (vs-1);
    int vlen = V_ >> lvs;
    int v0   = vc * vlen;
    int n    = qt*64 + lane;
    bool act = (n < N);
    if (tid < 64) lb[tid] = ~0ull;
    __syncthreads();

    const float4* zp = (const float4*)(z + (size_t)(act ? n : 0)*C_);
    float zr[32];
    #pragma unroll
    for (int cc = 0; cc < 8; ++cc) {
        float4 t = zp[cc];
        zr[cc*4+0]=t.x; zr[cc*4+1]=t.y; zr[cc*4+2]=t.z; zr[cc*4+3]=t.w;
    }

    float dmin = __builtin_inff();
    int imin = 0;
    const float* p = embp + (size_t)v0*ESTRIDE;
    f32x16 A0, B0, A1, B1;
    float e0, e1;
    sload_row(p, A0, B0, e0); p += ESTRIDE;
    for (int v2 = 0; v2 < vlen; v2 += 2) {
        asm volatile("s_waitcnt lgkmcnt(0)" ::: "memory");
        __builtin_amdgcn_sched_barrier(0);
        sload_row(p, A1, B1, e1); p += ESTRIDE;
        VSTEP(A0, B0, e0, v0 + v2);
        asm volatile("s_waitcnt lgkmcnt(0)" ::: "memory");
        __builtin_amdgcn_sched_barrier(0);
        sload_row(p, A0, B0, e0); p += ESTRIDE;
        VSTEP(A1, B1, e1, v0 + v2 + 1);
    }

    unsigned long long key =
        ((unsigned long long)fkey(dmin) << 32) | (unsigned int)imin;
    atomicMin(&lb[lane], key);
    __syncthreads();
    if (tid < 64) {
        int n0 = ((blockIdx.x*4) >> lvs)*64 + tid;
        if (n0 < N) atomicMin(best + n0, lb[tid]);
    }
}

__device__ __forceinline__ void cubic_taps(int i, int pn, float* wt, int* col) {
    double src = ((double)i + 0.5) * ((double)pn / 16.0) - 0.5;
    double fl = floor(src);
    const double A = -0.75;
    #pragma unroll
    for (int k = 0; k < 4; ++k) {
        double j = fl - 1.0 + (double)k;
        double d = fabs(src - j);
        double w;
        if (d <= 1.0)      w = ((A+2.0)*d - (A+3.0))*d*d + 1.0;
        else if (d < 2.0)  w = ((A*d - 5.0*A)*d + 8.0*A)*d - 4.0*A;
        else               w = 0.0;
        wt[k] = (float)w;
        int jj = (int)j;
        col[k] = jj < 0 ? 0 : (jj > pn-1 ? pn-1 : jj);
    }
}

// bicubic upsample (emb gather) -> LDS, 3x3 conv + Phi blend,
// f_hat += , f_rest -= , loss partial
__global__ void __launch_bounds__(256) k_upphi(
    const unsigned long long* __restrict__ best,
    const float* __restrict__ emb,
    const float* __restrict__ cw, const float* __restrict__ cb,
    const float* __restrict__ forig,
    float* __restrict__ f_hat, float* __restrict__ f_rest,
    float* __restrict__ lossAcc, int pn)
{
    __shared__ float hup[16][16][33];
    __shared__ float red[4];
    int bi = blockIdx.x >> 3;
    int g  = blockIdx.x & 7;
    int tid = threadIdx.x;
    int h = tid >> 4, w = tid & 15;

    float wh[4]; int th[4];
    float wwt[4]; int tw[4];
    cubic_taps(h, pn, wh, th);
    cubic_taps(w, pn, wwt, tw);

    float acc[32];
    #pragma unroll
    for (int c = 0; c < 32; ++c) acc[c] = 0.f;
    const unsigned long long* bptr = best + bi*pn*pn;
    for (int i = 0; i < 4; ++i) {
        if (wh[i] == 0.f) continue;
        for (int j = 0; j < 4; ++j) {
            float wt = wh[i]*wwt[j];
            if (wt == 0.f) continue;
            unsigned int idx = (unsigned int)(bptr[th[i]*pn + tw[j]] & 0xffffffffull);
            const float4* e4 = (const float4*)(emb + (size_t)idx*C_);
            #pragma unroll
            for (int cc = 0; cc < 8; ++cc) {
                float4 ev = e4[cc];
                acc[cc*4+0] = fmaf(wt, ev.x, acc[cc*4+0]);
                acc[cc*4+1] = fmaf(wt, ev.y, acc[cc*4+1]);
                acc[cc*4+2] = fmaf(wt, ev.z, acc[cc*4+2]);
                acc[cc*4+3] = fmaf(wt, ev.w, acc[cc*4+3]);
            }
        }
    }
    #pragma unroll
    for (int c = 0; c < 32; ++c) hup[h][w][c] = acc[c];
    __syncthreads();

    int co0 = g*4;
    float o4[4];
    #pragma unroll
    for (int k = 0; k < 4; ++k) o4[k] = cb[co0+k];
    for (int ci = 0; ci < 32; ++ci) {
        float hv[9];
        #pragma unroll
        for (int dh = 0; dh < 3; ++dh) {
            int hh = h + dh - 1;
            #pragma unroll
            for (int dw = 0; dw < 3; ++dw) {
                int ww2 = w + dw - 1;
                bool ok = (hh >= 0) & (hh < 16) & (ww2 >= 0) & (ww2 < 16);
                hv[dh*3+dw] = ok ? hup[hh & 15][ww2 & 15][ci] : 0.f;
            }
        }
        #pragma unroll
        for (int k = 0; k < 4; ++k) {
            const float* wr = cw + ((size_t)(co0+k)*C_ + ci)*9;
            float s = 0.f;
            #pragma unroll
            for (int p2 = 0; p2 < 9; ++p2) s = fmaf(hv[p2], wr[p2], s);
            o4[k] += s;
        }
    }

    float sq = 0.f;
    #pragma unroll
    for (int k = 0; k < 4; ++k) {
        float hv0 = hup[h][w][co0+k];
        float outv = 0.5f*hv0 + 0.5f*o4[k];
        size_t off = ((size_t)(bi*C_ + co0 + k))*HW_ + h*16 + w;
        float fh = f_hat[off] + outv;
        f_hat[off] = fh;
        f_rest[off] = f_rest[off] - outv;
        float df = fh - forig[off];
        sq = fmaf(df, df, sq);
    }
    #pragma unroll
    for (int o2 = 32; o2 > 0; o2 >>= 1) sq += __shfl_down(sq, o2, 64);
    if ((tid & 63) == 0) red[tid >> 6] = sq;
    __syncthreads();
    if (tid == 0) atomicAdd(lossAcc, (red[0]+red[1])+(red[2]+red[3]));
}

__global__ void __launch_bounds__(256) k_final(
    const float* __restrict__ f_hat, const float* __restrict__ lossAcc,
    float* __restrict__ out)
{
    int i = blockIdx.x*256 + threadIdx.x;
    if (i < NELEM) out[i] = f_hat[i];
    if (i == 0) out[NELEM] = lossAcc[0] * 1.25f / ((float)NELEM * 10.f);
}

extern "C" void kernel_launch(void* const* d_in, const int* in_sizes, int n_in,
                              void* d_out, int out_size, void* d_ws, size_t ws_size,
                              hipStream_t stream)
{
    const float* f   = (const float*)d_in[0];
    const float* emb = (const float*)d_in[1];
    const float* cw  = (const float*)d_in[2];
    const float* cb  = (const float*)d_in[3];
    float* out = (float*)d_out;
    char* ws = (char*)d_ws;
    unsigned long long* best = (unsigned long long*)ws;       // 8192 * 8 B
    float* f_rest = (float*)(ws + 65536);
    float* f_hat  = f_rest + NELEM;
    float* z      = f_hat + NELEM;
    float* embp   = z + NELEM;                    // (V_+2)*ESTRIDE floats
    float* lossAcc = embp + (size_t)(V_+2)*ESTRIDE;

    // Replicate PHI_IDX with numpy-linspace double semantics (no FP contraction)
    volatile double a   = 1.0/3.0/4.0;
    volatile double bb  = 1.0 - a;
    volatile double stp = (bb - a) / 3.0;
    double ticks[4];
    for (int i = 0; i < 4; ++i) { volatile double m = (double)i * stp; ticks[i] = m + a; }
    ticks[3] = bb;
    static const int pns[10] = {1,2,3,4,5,6,8,10,13,16};
    int phi_idx[10];
    for (int si = 0; si < 10; ++si) {
        volatile double x = (double)si / 9.0;
        int bi = 0; double bd = fabs(ticks[0] - x);
        for (int k = 1; k < 4; ++k) {
            double d = fabs(ticks[k] - x);
            if (d < bd) { bd = d; bi = k; }
        }
        phi_idx[si] = bi;
    }

    k_init<<<1024, 256, 0, stream>>>(f, emb, f_rest, f_hat, embp, lossAcc);

    // V-split log2 per scale: target >=2048 waves where possible, vlen >= 64
    static const int lvss[10] = {7,7,7,7,7,7,7,6,6,5};
    for (int si = 0; si < 10; ++si) {
        int pn = pns[si];
        int N = B_*pn*pn;
        int pthr = N*C_;
        k_pool<<<(pthr+255)/256, 256, 0, stream>>>(f_rest, z, best, pn, N);
        int qtiles = (N+63)/64;
        int lvs = lvss[si];
        int waves = qtiles << lvs;
        k_vq<<<waves/4, 256, 0, stream>>>(z, embp, best, N, lvs);
        const float* cwp = cw + (size_t)phi_idx[si]*C_*C_*9;
        const float* cbp = cb + (size_t)phi_idx[si]*C_;
        k_upphi<<<B_*8, 256, 0, stream>>>(best, emb, cwp, cbp, f, f_hat, f_rest,
                                          lossAcc, pn);
    }
    k_final<<<1024, 256, 0, stream>>>(f_hat, lossAcc, out);
}